// Round 3
// baseline (953.763 us; speedup 1.0000x reference)
//
#include <hip/hip_runtime.h>
#include <hip/hip_bf16.h>

#define BSZ 128
#define NSQ 1024
#define NSTEPC 8
#define IND 768
#define HIDD 512
#define G4D 2048
#define MLPD 512
#define NEGV -100000.0f
#define KSGATE 4  // K-split for gates gemm (1280 = 4 x 320)
#define MSPLIT 4  // m-split for scores kernel

typedef __attribute__((ext_vector_type(4))) float f32x4;
typedef __attribute__((ext_vector_type(8))) short short8v;

__device__ __forceinline__ void gl16(const unsigned short* g, unsigned short* l) {
  __builtin_amdgcn_global_load_lds(
      (const __attribute__((address_space(1))) unsigned int*)(g),
      (__attribute__((address_space(3))) unsigned int*)(l), 16, 0, 0);
}

__device__ __forceinline__ void split2(float4 f0, float4 f1, short8v& hi, short8v& lo) {
  float fv[8] = {f0.x, f0.y, f0.z, f0.w, f1.x, f1.y, f1.z, f1.w};
#pragma unroll
  for (int j = 0; j < 8; ++j) {
    const unsigned ub = __builtin_bit_cast(unsigned, fv[j]);
    const unsigned hb = ub & 0xFFFF0000u;
    const float lf = fv[j] - __builtin_bit_cast(float, hb);
    hi[j] = (short)(hb >> 16);
    lo[j] = (short)(__builtin_bit_cast(unsigned, lf) >> 16);
  }
}

// tanh(x) = 1 - 2/(e^{2x}+1)
__device__ __forceinline__ float tanh_fast(float x) {
  x = fminf(fmaxf(x, -15.0f), 15.0f);
  float e = __builtin_amdgcn_exp2f(x * 2.8853900817779268f);
  float r = __builtin_amdgcn_rcpf(e + 1.0f);
  return fmaf(-2.0f, r, 1.0f);
}

// ---------------- one-time: split W1c and [W_ih|W_hh] into bf16 hi/lo planes,
// tiled layout: unit16B = ((rb*NT + tile)*128 + row128)*4 + slot, slot = c4 ^ ((row>>1)&3)
__global__ __launch_bounds__(256) void k_prep_w(
    const float* __restrict__ W1c, const float* __restrict__ W_ih,
    const float* __restrict__ W_hh,
    unsigned short* __restrict__ wch, unsigned short* __restrict__ wcl,
    unsigned short* __restrict__ wgh, unsigned short* __restrict__ wgl) {
  int c = blockIdx.x * 256 + threadIdx.x;
  const float* src;
  unsigned short *dh, *dl;
  size_t unit;
  if (c < 49152) {  // W1c: 512 rows x 96 chunks (NT=24)
    const int row = c / 96, wc = c - row * 96;
    const int tile = wc >> 2, c4 = wc & 3;
    const int slot = c4 ^ ((row >> 1) & 3);
    unit = ((size_t)((row >> 7) * 24 + tile) * 128 + (row & 127)) * 4 + slot;
    src = W1c + (size_t)row * IND + wc * 8;
    dh = wch; dl = wcl;
  } else {
    c -= 49152;
    if (c >= 327680) return;  // Wg: 2048 rows x 160 chunks (NT=40)
    const int row = c / 160, wc = c - row * 160;
    const int k0 = wc * 8;
    const int tile = wc >> 2, c4 = wc & 3;
    const int slot = c4 ^ ((row >> 1) & 3);
    unit = ((size_t)((row >> 7) * 40 + tile) * 128 + (row & 127)) * 4 + slot;
    src = (k0 < IND) ? (W_ih + (size_t)row * IND + k0)
                     : (W_hh + (size_t)row * HIDD + (k0 - IND));
    dh = wgh; dl = wgl;
  }
  const float4 f0 = *(const float4*)src, f1 = *(const float4*)(src + 4);
  short8v hi, lo;
  split2(f0, f1, hi, lo);
  *(short8v*)(dh + unit * 8) = hi;
  *(short8v*)(dl + unit * 8) = lo;
}

// ---------------- init: mask, c=0, lp=0, xh planes = [split(target_emb) | 0]
__global__ __launch_bounds__(256) void k_init2(
    const float* __restrict__ te, const int* __restrict__ cl,
    float* __restrict__ mask, float* __restrict__ cst, float* __restrict__ lp,
    unsigned short* __restrict__ xhh, unsigned short* __restrict__ xhl) {
  const int b = blockIdx.x, tid = threadIdx.x;
  const int L = cl[b];
  for (int n = tid; n < NSQ; n += 256) mask[(size_t)b * NSQ + n] = (n >= L) ? NEGV : 0.0f;
  for (int j = tid; j < HIDD; j += 256) cst[(size_t)b * HIDD + j] = 0.0f;
  if (tid == 0) lp[b] = 0.0f;
  if (tid < 160) {  // 160 chunks per row (K=1280)
    const int tile = tid >> 2, c4 = tid & 3;
    const int slot = c4 ^ ((b >> 1) & 3);
    const size_t ub = (((size_t)tile * 128 + b) * 4 + slot) * 8;
    short8v hi = {}, lo = {};
    if (tid < 96) {
      const float* s = te + (size_t)b * IND + tid * 8;
      split2(*(const float4*)s, *(const float4*)(s + 4), hi, lo);
    }
    *(short8v*)&xhh[ub] = hi;
    *(short8v*)&xhl[ub] = lo;
  }
}

// ---------------- ctx_part GEMM (split-bf16, 3 MFMA products)
// cp[b][m][n] = sum_k ctx[b,n,k]*W1c[m,k] + b1[m]
// block: 256 thr / 4 waves, tile m=256 (wave owns 64), n=64, K=768 (24 tiles)
// W staged from pre-split planes via global_load_lds; ctx reg-split in-kernel.
__global__ __launch_bounds__(256) void k_ctx2(
    const float* __restrict__ ctx,
    const unsigned short* __restrict__ wch, const unsigned short* __restrict__ wcl,
    const float* __restrict__ bias, const int* __restrict__ clen,
    float* __restrict__ cp) {
  __shared__ __align__(16) unsigned short sWh[8192], sWl[8192];  // 256 rows x 32
  __shared__ __align__(16) unsigned short sCh[2048], sCl[2048];  // 64 rows x 32
  const int i0 = blockIdx.y * 64;
  const int b = i0 >> 10;
  const int nbase = i0 & 1023;
  if (nbase >= clen[b]) return;
  const int m0 = blockIdx.x * 256;
  const int rb0 = blockIdx.x * 2;
  const int tid = threadIdx.x;
  const int lane = tid & 63, wid = tid >> 6;
  const int l15 = lane & 15, l4 = lane >> 4;
  const int crow = tid >> 2, cc4 = tid & 3;
  const int ckread = cc4 ^ ((crow >> 1) & 3);
  const float* csrc = ctx + (size_t)(i0 + crow) * IND + ckread * 8;

  f32x4 acc[4][4] = {};  // [fm][fn]
  for (int t = 0; t < 24; ++t) {
#pragma unroll
    for (int i = 0; i < 8; ++i) {  // stage W: 32KB via 8x gload_lds per thread
      const int v = wid * 1024 + i * 4096;
      const int plane = v >> 14;
      const int rem = v & 16383;
      const int rbh = rem >> 13;
      const int offs = (rem & 8191) >> 1;  // shorts
      const unsigned short* g = (plane ? wcl : wch) +
          ((size_t)((rb0 + rbh) * 24 + t)) * 4096 + offs + lane * 8;
      unsigned short* l = (plane ? sWl : sWh) + rbh * 4096 + offs;
      gl16(g, l);
    }
    {  // stage ctx: reg-split, linear tid*16 ds_write (0-conflict), pre-swizzled src
      const float* s = csrc + t * 32;
      short8v hi, lo;
      split2(*(const float4*)s, *(const float4*)(s + 4), hi, lo);
      *(short8v*)&sCh[tid * 8] = hi;
      *(short8v*)&sCl[tid * 8] = lo;
    }
    __syncthreads();
    short8v ah[4], al[4], bh[4], bl[4];
#pragma unroll
    for (int f = 0; f < 4; ++f) {
      const int rw = wid * 64 + f * 16 + l15;
      const int sw = l4 ^ ((rw >> 1) & 3);
      ah[f] = *(const short8v*)&sWh[rw * 32 + sw * 8];
      al[f] = *(const short8v*)&sWl[rw * 32 + sw * 8];
      const int rc = f * 16 + l15;
      const int sc = l4 ^ ((rc >> 1) & 3);
      bh[f] = *(const short8v*)&sCh[rc * 32 + sc * 8];
      bl[f] = *(const short8v*)&sCl[rc * 32 + sc * 8];
    }
#pragma unroll
    for (int fm = 0; fm < 4; ++fm)
#pragma unroll
      for (int fn = 0; fn < 4; ++fn) {
        acc[fm][fn] = __builtin_amdgcn_mfma_f32_16x16x32_bf16(ah[fm], bh[fn], acc[fm][fn], 0, 0, 0);
        acc[fm][fn] = __builtin_amdgcn_mfma_f32_16x16x32_bf16(ah[fm], bl[fn], acc[fm][fn], 0, 0, 0);
        acc[fm][fn] = __builtin_amdgcn_mfma_f32_16x16x32_bf16(al[fm], bh[fn], acc[fm][fn], 0, 0, 0);
      }
    __syncthreads();
  }
#pragma unroll
  for (int fm = 0; fm < 4; ++fm) {
#pragma unroll
    for (int r = 0; r < 4; ++r) {
      const int m = m0 + wid * 64 + fm * 16 + l4 * 4 + r;
      const float bb = bias[m];
      float* dst = cp + (((size_t)(b * MLPD + m)) << 10) + nbase + l15;
#pragma unroll
      for (int fn = 0; fn < 4; ++fn)
        dst[fn * 16] = acc[fm][fn][r] + bb;
    }
  }
}

// ---------------- gates GEMM: gp[ks][i][n] partial over K-chunk ks (320 wide)
// pure 2-plane bf16 MFMA; A = xh planes [128][1280], B = Wg planes [2048][1280]
__global__ __launch_bounds__(256) void k_gates(
    const unsigned short* __restrict__ xhh, const unsigned short* __restrict__ xhl,
    const unsigned short* __restrict__ wgh, const unsigned short* __restrict__ wgl,
    float* __restrict__ gp) {
  __shared__ __align__(16) unsigned short sAh[4096], sAl[4096], sBh[4096], sBl[4096];
  const int nb = blockIdx.x;  // n-block (16)
  const int ks = blockIdx.y;  // K-chunk (4)
  const int tid = threadIdx.x;
  const int lane = tid & 63, wid = tid >> 6;
  const int wm = wid >> 1, wn = wid & 1;
  const int l15 = lane & 15, l4 = lane >> 4;
  f32x4 acc[4][4] = {};  // [fi][fn]
  for (int t = 0; t < 10; ++t) {
    const int gt = ks * 10 + t;
#pragma unroll
    for (int i = 0; i < 8; ++i) {
      const int v = wid * 1024 + i * 4096;
      const int mm = v >> 13;  // 0..3: Ah, Al, Bh, Bl
      const int offs = (v & 8191) >> 1;
      const unsigned short* g;
      unsigned short* l;
      if (mm == 0)      { g = xhh + (size_t)gt * 4096 + offs; l = sAh + offs; }
      else if (mm == 1) { g = xhl + (size_t)gt * 4096 + offs; l = sAl + offs; }
      else if (mm == 2) { g = wgh + ((size_t)nb * 40 + gt) * 4096 + offs; l = sBh + offs; }
      else              { g = wgl + ((size_t)nb * 40 + gt) * 4096 + offs; l = sBl + offs; }
      gl16(g + lane * 8, l);
    }
    __syncthreads();
    short8v ahv[4], alv[4], bhv[4], blv[4];
#pragma unroll
    for (int f = 0; f < 4; ++f) {
      const int ri = wm * 64 + f * 16 + l15;
      const int sa = l4 ^ ((ri >> 1) & 3);
      ahv[f] = *(const short8v*)&sAh[ri * 32 + sa * 8];
      alv[f] = *(const short8v*)&sAl[ri * 32 + sa * 8];
      const int rn = wn * 64 + f * 16 + l15;
      const int sb = l4 ^ ((rn >> 1) & 3);
      bhv[f] = *(const short8v*)&sBh[rn * 32 + sb * 8];
      blv[f] = *(const short8v*)&sBl[rn * 32 + sb * 8];
    }
#pragma unroll
    for (int fi = 0; fi < 4; ++fi)
#pragma unroll
      for (int fn = 0; fn < 4; ++fn) {
        acc[fi][fn] = __builtin_amdgcn_mfma_f32_16x16x32_bf16(ahv[fi], bhv[fn], acc[fi][fn], 0, 0, 0);
        acc[fi][fn] = __builtin_amdgcn_mfma_f32_16x16x32_bf16(ahv[fi], blv[fn], acc[fi][fn], 0, 0, 0);
        acc[fi][fn] = __builtin_amdgcn_mfma_f32_16x16x32_bf16(alv[fi], bhv[fn], acc[fi][fn], 0, 0, 0);
      }
    __syncthreads();
  }
#pragma unroll
  for (int fi = 0; fi < 4; ++fi) {
#pragma unroll
    for (int r = 0; r < 4; ++r) {
      const int i = wm * 64 + fi * 16 + l4 * 4 + r;
      float* dst = gp + ((size_t)ks * BSZ + i) * G4D + nb * 128 + wn * 64 + l15;
#pragma unroll
      for (int fn = 0; fn < 4; ++fn)
        dst[fn * 16] = acc[fi][fn][r];
    }
  }
}

// ---------------- gate reduce + LSTM activations + h-plane write + fused hproj
__global__ __launch_bounds__(512) void k_lstm2(
    const float* __restrict__ gp, const float* __restrict__ b_ih,
    const float* __restrict__ b_hh, const float* __restrict__ W1h,
    float* __restrict__ cst,
    unsigned short* __restrict__ xhh, unsigned short* __restrict__ xhl,
    float* __restrict__ hpp) {
  __shared__ float hs[HIDD];
  const int b = blockIdx.x, j = threadIdx.x;
  float g[4];
#pragma unroll
  for (int q = 0; q < 4; ++q) {
    float s = b_ih[q * HIDD + j] + b_hh[q * HIDD + j];
#pragma unroll
    for (int ks = 0; ks < KSGATE; ++ks)
      s += gp[((size_t)ks * BSZ + b) * G4D + q * HIDD + j];
    g[q] = s;
  }
  const float c_old = cst[(size_t)b * HIDD + j];
  const float ig = 1.0f / (1.0f + expf(-g[0]));
  const float fg = 1.0f / (1.0f + expf(-g[1]));
  const float gg = tanhf(g[2]);
  const float og = 1.0f / (1.0f + expf(-g[3]));
  const float cn = fg * c_old + ig * gg;
  const float hn = og * tanhf(cn);
  cst[(size_t)b * HIDD + j] = cn;
  hs[j] = hn;
  // write h into xh planes at k = 768 + j
  {
    const int tile = 24 + (j >> 5);
    const int c4 = (j >> 3) & 3;
    const int slot = c4 ^ ((b >> 1) & 3);
    const size_t u16i = (((size_t)tile * 128 + b) * 4 + slot) * 8 + (j & 7);
    const unsigned ubh = __builtin_bit_cast(unsigned, hn) & 0xFFFF0000u;
    const float lf = hn - __builtin_bit_cast(float, ubh);
    xhh[u16i] = (unsigned short)(ubh >> 16);
    xhl[u16i] = (unsigned short)(__builtin_bit_cast(unsigned, lf) >> 16);
  }
  __syncthreads();
  // fused hproj: hp[b][m] = sum_k h[k] * W1h[m][k], m = j
  const float* wr = W1h + (size_t)j * HIDD;
  float s = 0.0f;
#pragma unroll 4
  for (int k = 0; k < HIDD; k += 4) {
    const float4 h4 = *(const float4*)&hs[k];
    const float4 w4 = *(const float4*)&wr[k];
    s = fmaf(h4.x, w4.x, fmaf(h4.y, w4.y, fmaf(h4.z, w4.z, fmaf(h4.w, w4.w, s))));
  }
  hpp[(size_t)b * HIDD + j] = s;
}

// ---------------- scores partial: psc[b][mh][n] = sum_m tanh(cp+hp)*w2
__global__ __launch_bounds__(256) void k_scores(
    const float* __restrict__ cp, const float* __restrict__ hpp,
    const float* __restrict__ w2, const int* __restrict__ clen,
    float* __restrict__ psc) {
  const int mh = blockIdx.x;
  const int b = blockIdx.y;
  const int tid = threadIdx.x;
  __shared__ float hsm[128], wsm[128];
  if (tid < 128) {
    hsm[tid] = hpp[(size_t)b * MLPD + mh * 128 + tid];
    wsm[tid] = w2[mh * 128 + tid];
  }
  __syncthreads();
  const int len = clen[b];
  const int n0 = tid * 4;
  if (n0 >= len) return;
  float ax = 0, ay = 0, az = 0, aw = 0;
  const float* base = cp + ((size_t)b * MLPD + mh * 128) * NSQ + n0;
#pragma unroll 4
  for (int mm = 0; mm < 128; ++mm) {
    const float4 c4 = *(const float4*)(base + (size_t)mm * NSQ);
    const float h = hsm[mm], w = wsm[mm];
    ax = fmaf(tanh_fast(c4.x + h), w, ax);
    ay = fmaf(tanh_fast(c4.y + h), w, ay);
    az = fmaf(tanh_fast(c4.z + h), w, az);
    aw = fmaf(tanh_fast(c4.w + h), w, aw);
  }
  *(float4*)(psc + ((size_t)b * MSPLIT + mh) * NSQ + n0) = make_float4(ax, ay, az, aw);
}

// ---------------- argmax + LSE + lp + mask update + x-plane feedback
__global__ __launch_bounds__(256) void k_argmax(
    const float* __restrict__ psc, float* __restrict__ mask,
    const float* __restrict__ gum, const float* __restrict__ b2p,
    float* __restrict__ lp, const float* __restrict__ ctx,
    unsigned short* __restrict__ xhh, unsigned short* __restrict__ xhl,
    float* __restrict__ outv, int step) {
  const int b = blockIdx.x, tid = threadIdx.x;
  __shared__ float rv[256], rs[256], rm[256];
  __shared__ int ri[256];
  __shared__ int sel;
  const float b2 = b2p[0];
  const int n0 = tid * 4;
  const float4 m4 = *(const float4*)(mask + (size_t)b * NSQ + n0);
  float sc[4] = {b2 + m4.x, b2 + m4.y, b2 + m4.z, b2 + m4.w};
#pragma unroll
  for (int mh = 0; mh < MSPLIT; ++mh) {
    const float4 p4 = *(const float4*)(psc + ((size_t)b * MSPLIT + mh) * NSQ + n0);
    sc[0] += p4.x; sc[1] += p4.y; sc[2] += p4.z; sc[3] += p4.w;
  }
  const float4 g4 = *(const float4*)(gum + ((size_t)step * BSZ + b) * NSQ + n0);
  const float gv[4] = {g4.x, g4.y, g4.z, g4.w};
  float bestv = -1e30f, bests = 0.0f, msc = -1e30f;
  int bestn = 0;
#pragma unroll
  for (int q = 0; q < 4; ++q) {
    const float v = sc[q] + gv[q];
    if (v > bestv) { bestv = v; bestn = n0 + q; bests = sc[q]; }
    msc = fmaxf(msc, sc[q]);
  }
  rv[tid] = bestv; ri[tid] = bestn; rs[tid] = bests; rm[tid] = msc;
  __syncthreads();
  for (int o = 128; o > 0; o >>= 1) {
    if (tid < o) {
      if (rv[tid + o] > rv[tid] || (rv[tid + o] == rv[tid] && ri[tid + o] < ri[tid])) {
        rv[tid] = rv[tid + o]; ri[tid] = ri[tid + o]; rs[tid] = rs[tid + o];
      }
      rm[tid] = fmaxf(rm[tid], rm[tid + o]);
    }
    __syncthreads();
  }
  const float M = rm[0];
  __syncthreads();
  float se = 0.0f;
#pragma unroll
  for (int q = 0; q < 4; ++q)
    se += __builtin_amdgcn_exp2f((sc[q] - M) * 1.4426950408889634f);
  rm[tid] = se;
  __syncthreads();
  for (int o = 128; o > 0; o >>= 1) {
    if (tid < o) rm[tid] += rm[tid + o];
    __syncthreads();
  }
  if (tid == 0) {
    const int n = ri[0];
    const float lse = M + logf(rm[0]);
    const float nlp = lp[b] + rs[0] - lse;
    lp[b] = nlp;
    mask[(size_t)b * NSQ + n] = NEGV;
    outv[step * BSZ + b] = (float)n;
    if (step == NSTEPC - 1) outv[NSTEPC * BSZ + b] = nlp;
    sel = n;
  }
  __syncthreads();
  const int n = sel;
  if (tid < 96) {  // x feedback: split ctx row into xh planes (96 chunks)
    const float* src = ctx + ((size_t)b * NSQ + n) * IND + tid * 8;
    const int tile = tid >> 2, c4 = tid & 3;
    const int slot = c4 ^ ((b >> 1) & 3);
    const size_t ub = (((size_t)tile * 128 + b) * 4 + slot) * 8;
    short8v hi, lo;
    split2(*(const float4*)src, *(const float4*)(src + 4), hi, lo);
    *(short8v*)&xhh[ub] = hi;
    *(short8v*)&xhl[ub] = lo;
  }
}

extern "C" void kernel_launch(void* const* d_in, const int* in_sizes, int n_in,
                              void* d_out, int out_size, void* d_ws, size_t ws_size,
                              hipStream_t stream) {
  const float* target_emb = (const float*)d_in[0];
  const float* ctx_emb   = (const float*)d_in[1];
  const int*   ctx_len   = (const int*)d_in[3];
  const float* W_ih = (const float*)d_in[5];
  const float* W_hh = (const float*)d_in[6];
  const float* b_ih = (const float*)d_in[7];
  const float* b_hh = (const float*)d_in[8];
  const float* W1c  = (const float*)d_in[9];
  const float* W1h  = (const float*)d_in[10];
  const float* b1   = (const float*)d_in[11];
  const float* w2   = (const float*)d_in[12];
  const float* b2   = (const float*)d_in[13];
  const float* gumbel = (const float*)d_in[14];
  float* out = (float*)d_out;

  float* ws = (float*)d_ws;
  size_t off = 0;
  auto alloc = [&](size_t n) { float* p = ws + off; off += (n + 63) & ~(size_t)63; return p; };

  float* cp   = alloc((size_t)BSZ * MLPD * NSQ);        // 268 MB
  float* gp   = alloc((size_t)KSGATE * BSZ * G4D);
  float* hpp  = alloc((size_t)BSZ * MLPD);
  float* psc  = alloc((size_t)BSZ * MSPLIT * NSQ);
  float* mask = alloc((size_t)BSZ * NSQ);
  float* cst  = alloc((size_t)BSZ * HIDD);
  float* lp   = alloc(128);
  unsigned short* wch = (unsigned short*)alloc(196608);   // 512x768 u16
  unsigned short* wcl = (unsigned short*)alloc(196608);
  unsigned short* wgh = (unsigned short*)alloc(1310720);  // 2048x1280 u16
  unsigned short* wgl = (unsigned short*)alloc(1310720);
  unsigned short* xhh = (unsigned short*)alloc(81920);    // 128x1280 u16
  unsigned short* xhl = (unsigned short*)alloc(81920);

  k_prep_w<<<1472, 256, 0, stream>>>(W1c, W_ih, W_hh, wch, wcl, wgh, wgl);
  k_init2<<<BSZ, 256, 0, stream>>>(target_emb, ctx_len, mask, cst, lp, xhh, xhl);
  k_ctx2<<<dim3(2, 2048), 256, 0, stream>>>(ctx_emb, wch, wcl, b1, ctx_len, cp);

  for (int t = 0; t < NSTEPC; ++t) {
    k_gates<<<dim3(16, KSGATE), 256, 0, stream>>>(xhh, xhl, wgh, wgl, gp);
    k_lstm2<<<BSZ, 512, 0, stream>>>(gp, b_ih, b_hh, W1h, cst, xhh, xhl, hpp);
    k_scores<<<dim3(MSPLIT, BSZ), 256, 0, stream>>>(cp, hpp, w2, ctx_len, psc);
    k_argmax<<<BSZ, 256, 0, stream>>>(psc, mask, gumbel, b2, lp, ctx_emb, xhh, xhl, out, t);
  }
}